// Round 14
// baseline (1045.354 us; speedup 1.0000x reference)
//
#include <hip/hip_runtime.h>
#include <hip/hip_bf16.h>
#include <cstdint>

#define SENT_LEN   256
#define SENT_BATCH 64
#define WORD_LEN   16
#define EMB        128
#define HID        256
#define CEMB       64
#define CHID       128
#define TAGS       50
#define K_IN       (EMB + CHID)   // 256
#define LOG2E      1.44269504f

typedef __attribute__((ext_vector_type(8))) short short8;
typedef __attribute__((ext_vector_type(4))) float f32x4;
typedef __attribute__((ext_vector_type(4))) int   i32x4;
typedef __attribute__((ext_vector_type(2))) long  lng2;

__device__ __forceinline__ float rcpf(float x) { return __builtin_amdgcn_rcpf(x); }
// inputs pre-scaled by log2e: sig2(xl) = sigmoid(xl/log2e), tanh2(xl) = tanh(xl/log2e)
__device__ __forceinline__ float sig2(float xl) {
    return rcpf(1.f + __builtin_amdgcn_exp2f(-xl));
}
__device__ __forceinline__ float tanh2(float xl) {
    xl = fminf(fmaxf(xl, -22.f), 22.f);
    float u = __builtin_amdgcn_exp2f(xl + xl);
    return (u - 1.f) * rcpf(u + 1.f);
}
__device__ __forceinline__ float lstm_act(float gi, float gf, float gg, float go, float& cst) {
    float c = sig2(gf) * cst + sig2(gi) * tanh2(gg);
    cst = c;
    return sig2(go) * tanh2(c * LOG2E);
}
__device__ __forceinline__ float bf_lo(unsigned u) { return __uint_as_float(u << 16); }
__device__ __forceinline__ float bf_hi(unsigned u) { return __uint_as_float(u & 0xffff0000u); }
// branch-free RNE bf16 (finite inputs only)
__device__ __forceinline__ unsigned short f2bfu(float f) {
    unsigned u = __float_as_uint(f);
    u += 0x7fff + ((u >> 16) & 1);
    return (unsigned short)(u >> 16);
}
// CK-style barrier: drains LDS (lgkmcnt) only — global prefetches stay in flight.
__device__ __forceinline__ void block_sync_lds() {
    asm volatile("s_waitcnt lgkmcnt(0)\ns_barrier" ::: "memory");
}
// 16-byte K-fragment MFMA as two K=32 i8 calls. Shared A/B k-permutation:
// frag position (lq, half, p) <-> source k = (base) + lq*16 + half*8 + p.
__device__ __forceinline__ i32x4 mfma_i8_k64(lng2 a, lng2 b, i32x4 c) {
    c = __builtin_amdgcn_mfma_i32_16x16x32_i8(a.x, b.x, c, 0, 0, 0);
    return __builtin_amdgcn_mfma_i32_16x16x32_i8(a.y, b.y, c, 0, 0, 0);
}

// ---------------- K1a: pre8[(ch*128+j)*4+gt] = LOG2E*(b_c[g] + Wih_c[g]·char_emb[ch]), g=gt*128+j
__global__ void prep_char(const float* __restrict__ Wih_c, const float* __restrict__ char_emb,
                          const float* __restrict__ bih_c, const float* __restrict__ bhh_c,
                          float* __restrict__ pre8) {
    int ch = blockIdx.x;      // 128
    int g  = threadIdx.x;     // 512
    float acc = bih_c[g] + bhh_c[g];
    const float* w = Wih_c + g * CEMB;
    const float* e = char_emb + ch * CEMB;
#pragma unroll
    for (int k = 0; k < CEMB; k++) acc += w[k] * e[k];
    int gt = g >> 7, j = g & 127;
    pre8[((ch * 128) + j) * 4 + gt] = acc * LOG2E;
}

// ---------------- K1b: per-row i8 quantization of Whh_w. 1024 blocks x 64.
__global__ void prep_wq(const float* __restrict__ Whh_w, signed char* __restrict__ wq,
                        float* __restrict__ sw) {
    int g = blockIdx.x;
    int lane = threadIdx.x;   // 64
    float4 v = reinterpret_cast<const float4*>(Whh_w + (size_t)g * HID)[lane];
    float m = fmaxf(fmaxf(fabsf(v.x), fabsf(v.y)), fmaxf(fabsf(v.z), fabsf(v.w)));
#pragma unroll
    for (int off = 32; off; off >>= 1) m = fmaxf(m, __shfl_xor(m, off, 64));
    m = fmaxf(m, 1e-20f);
    float inv = 127.f / m;
    int q0 = __float2int_rn(v.x * inv), q1 = __float2int_rn(v.y * inv);
    int q2 = __float2int_rn(v.z * inv), q3 = __float2int_rn(v.w * inv);
    int packed = (q0 & 255) | ((q1 & 255) << 8) | ((q2 & 255) << 16) | ((q3 & 255) << 24);
    reinterpret_cast<int*>(wq)[g * 64 + lane] = packed;
    if (lane == 0) sw[g] = m / 127.f;
}

// ---------------- K2: char LSTM. 256 blocks x 1 chain, 512 threads (8 waves).
// Wave w owns gate types i,f,g,o for dims j = w*16 + l15. Whh_c i8 in-kernel quant.
// A-pack = the contiguous h i8 vector (128 B, dbuf). Quad (kt,lq) reads the 16B
// chunk h[kt*64+lq*16 .. +15]: quad-uniform address (LDS broadcast), conflict-free.
__global__ __launch_bounds__(512, 1) void char_lstm(
        const int* __restrict__ words, const float* __restrict__ Whh_c,
        const float* __restrict__ pre8, float* __restrict__ cf) {
    int t    = blockIdx.x;               // chain
    int tid  = threadIdx.x;
    int lane = tid & 63, w = tid >> 6;   // 8 waves
    int l15  = lane & 15, lq = lane >> 4;
    int j    = w * 16 + l15;

    __shared__ __align__(16) signed char hv[2][128];   // h as i8, dbuf, 256 B

    // ---- in-kernel per-row i8 quant of Whh_c; B-frag (nt,kt): k = kt*64 + lq*16 + p
    lng2 bfr[4][2];
    float swl[4];
#pragma unroll
    for (int nt = 0; nt < 4; nt++) {
        const float* wr = Whh_c + (size_t)(nt * 128 + j) * CHID;
        float v[2][16];
        float m = 0.f;
#pragma unroll
        for (int kt = 0; kt < 2; kt++) {
#pragma unroll
            for (int q = 0; q < 4; q++) {
                float4 f = reinterpret_cast<const float4*>(wr + kt * 64 + lq * 16 + q * 4)[0];
                v[kt][q * 4 + 0] = f.x; v[kt][q * 4 + 1] = f.y;
                v[kt][q * 4 + 2] = f.z; v[kt][q * 4 + 3] = f.w;
            }
#pragma unroll
            for (int p = 0; p < 16; p++) m = fmaxf(m, fabsf(v[kt][p]));
        }
        m = fmaxf(m, __shfl_xor(m, 16, 64));
        m = fmaxf(m, __shfl_xor(m, 32, 64));
        m = fmaxf(m, 1e-20f);
        float inv = 127.f / m;
#pragma unroll
        for (int kt = 0; kt < 2; kt++) {
            unsigned long lo = 0, hi = 0;
#pragma unroll
            for (int p = 0; p < 8; p++) {
                lo |= (unsigned long)((unsigned)__float2int_rn(v[kt][p] * inv) & 255) << (8 * p);
                hi |= (unsigned long)((unsigned)__float2int_rn(v[kt][p + 8] * inv) & 255) << (8 * p);
            }
            lng2 bb; bb.x = (long)lo; bb.y = (long)hi;
            bfr[nt][kt] = bb;
        }
        swl[nt] = m * (LOG2E / (127.f * 127.f));
    }
    if (tid < 64) { reinterpret_cast<int*>(hv)[tid] = 0; }

    float cst = 0.f;
    const float4* pre4p = reinterpret_cast<const float4*>(pre8);
    int cid0 = words[t];
    int cid1 = words[SENT_LEN + t];
    float4 pr0 = pre4p[cid0 * 128 + j];
    float4 pr1 = pre4p[cid1 * 128 + j];
    int cidn0 = words[2 * SENT_LEN + t];
    int cidn1 = words[3 * SENT_LEN + t];
    __syncthreads();

    for (int u = 0; u < 512; u++) {          // steps 2u (A), 2u+1 (B)
        float4 prn0 = pre4p[cidn0 * 128 + j];
        float4 prn1 = pre4p[cidn1 * 128 + j];
        cidn0 = words[(((u << 1) + 4) & 1023) * SENT_LEN + t];
        cidn1 = words[(((u << 1) + 5) & 1023) * SENT_LEN + t];

        {   // step A: read hv[0] -> write hv[1]
            const lng2* hp = reinterpret_cast<const lng2*>(hv[0]);
            lng2 a0 = hp[lq];            // h[lq*16 .. +15]
            lng2 a1 = hp[4 + lq];        // h[64 + lq*16 .. +15]
            i32x4 acc[4] = {};
#pragma unroll
            for (int nt = 0; nt < 4; nt++) {
                acc[nt] = mfma_i8_k64(a0, bfr[nt][0], acc[nt]);
                acc[nt] = mfma_i8_k64(a1, bfr[nt][1], acc[nt]);
            }
            float gi = (float)acc[0][0] * swl[0] + pr0.x;
            float gf = (float)acc[1][0] * swl[1] + pr0.y;
            float gg = (float)acc[2][0] * swl[2] + pr0.z;
            float go = (float)acc[3][0] * swl[3] + pr0.w;
            float h = lstm_act(gi, gf, gg, go, cst);
            if (lq == 0)
                hv[1][j] = (signed char)__float2int_rn(h * 127.f);
            block_sync_lds();
        }
        {   // step B: read hv[1] -> write hv[0]
            const lng2* hp = reinterpret_cast<const lng2*>(hv[1]);
            lng2 a0 = hp[lq];
            lng2 a1 = hp[4 + lq];
            i32x4 acc[4] = {};
#pragma unroll
            for (int nt = 0; nt < 4; nt++) {
                acc[nt] = mfma_i8_k64(a0, bfr[nt][0], acc[nt]);
                acc[nt] = mfma_i8_k64(a1, bfr[nt][1], acc[nt]);
            }
            float gi = (float)acc[0][0] * swl[0] + pr1.x;
            float gf = (float)acc[1][0] * swl[1] + pr1.y;
            float gg = (float)acc[2][0] * swl[2] + pr1.z;
            float go = (float)acc[3][0] * swl[3] + pr1.w;
            float h = lstm_act(gi, gf, gg, go, cst);
            if (lq == 0) {
                hv[0][j] = (signed char)__float2int_rn(h * 127.f);
                if ((u & 7) == 7)
                    cf[((size_t)t * SENT_BATCH + (u >> 3)) * CHID + j] = h;
            }
            block_sync_lds();
        }
        pr0 = prn0; pr1 = prn1;
    }
}

// ---------------- K3: bf16 MFMA GEMM with REGISTER-RESIDENT B + 4-t A reuse.
// Grid (8, 64): bx -> j0 = bx*32 (32 dims), by -> tg = by*4 (4 time steps).
// 256 thr = 4 waves; wave wv owns N-tiles {2wv, 2wv+1}; N-row n = nt*16 + l15 maps to
// (dim = nt*4 + (l15>>2), gate = l15&3). B-frags loaded once (64 VGPR), reused 4 t's.
// Stores 4 gate-ushorts per (b,t,dim) at the SAME byte addresses as the old uint2
// layout: ushort index ((b*256+t)*1024 + dim*4 + gate)  => word_lstm unchanged.
#define XA_SEG 65   // 16B units per LDS segment (64 lanes + 1 pad)
__global__ __launch_bounds__(256, 2) void xw_gemm(
        const int* __restrict__ sentences, const float* __restrict__ word_emb,
        const float* __restrict__ cf, const float* __restrict__ Wih_w,
        const float* __restrict__ bih_w, const float* __restrict__ bhh_w,
        unsigned short* __restrict__ xw) {
    __shared__ short8 Apack[32 * XA_SEG];   // segment s = kt*4 + mt
    __shared__ int sid_s[256];
    int tid = threadIdx.x;
    int lane = tid & 63, wv = tid >> 6, l15 = lane & 15, lq = lane >> 4;
    int j0 = blockIdx.x * 32;
    int tg = blockIdx.y * 4;

    sid_s[tid] = sentences[tg * 64 + tid];   // 4 t's worth of sentence ids

    // ---- B-frags (bf16) + biases, register-resident
    short8 bfr[2][8];
    float bb[2];
#pragma unroll
    for (int q = 0; q < 2; q++) {
        int nt = 2 * wv + q;
        int grow = (l15 & 3) * 256 + j0 + nt * 4 + (l15 >> 2);   // gate*256 + dim
        const float* wr = Wih_w + (size_t)grow * K_IN;
#pragma unroll
        for (int kt = 0; kt < 8; kt++) {
            float4 f0 = reinterpret_cast<const float4*>(wr + kt * 32 + lq * 8)[0];
            float4 f1 = reinterpret_cast<const float4*>(wr + kt * 32 + lq * 8 + 4)[0];
            short8 bv;
            bv[0] = (short)f2bfu(f0.x); bv[1] = (short)f2bfu(f0.y);
            bv[2] = (short)f2bfu(f0.z); bv[3] = (short)f2bfu(f0.w);
            bv[4] = (short)f2bfu(f1.x); bv[5] = (short)f2bfu(f1.y);
            bv[6] = (short)f2bfu(f1.z); bv[7] = (short)f2bfu(f1.w);
            bfr[q][kt] = bv;
        }
        bb[q] = bih_w[grow] + bhh_w[grow];
    }

    for (int tt = 0; tt < 4; tt++) {
        int t = tg + tt;
        __syncthreads();   // protect Apack from previous iteration's readers (and sid_s at tt=0)
#pragma unroll
        for (int it = 0; it < 8; it++) {   // stage A(t): 64 rows x 256 k, bf16 frag layout
            int idx = it * 256 + tid;
            int m = idx >> 5, k8 = idx & 31;
            int k = k8 * 8;
            int kt = k8 >> 2, lqs = k8 & 3;
            const float* asrc = (k < EMB)
                ? word_emb + (size_t)sid_s[tt * 64 + m] * EMB + k
                : cf + (size_t)(t * 64 + m) * CHID + (k - EMB);
            float4 a0 = reinterpret_cast<const float4*>(asrc)[0];
            float4 a1 = reinterpret_cast<const float4*>(asrc)[1];
            short8 av;
            av[0] = (short)f2bfu(a0.x); av[1] = (short)f2bfu(a0.y);
            av[2] = (short)f2bfu(a0.z); av[3] = (short)f2bfu(a0.w);
            av[4] = (short)f2bfu(a1.x); av[5] = (short)f2bfu(a1.y);
            av[6] = (short)f2bfu(a1.z); av[7] = (short)f2bfu(a1.w);
            Apack[(kt * 4 + (m >> 4)) * XA_SEG + (m & 15) + (lqs << 4)] = av;
        }
        __syncthreads();

        f32x4 acc[4][2] = {};
#pragma unroll
        for (int kt = 0; kt < 8; kt++) {
#pragma unroll
            for (int mt = 0; mt < 4; mt++) {
                short8 a = Apack[(kt * 4 + mt) * XA_SEG + lane];
#pragma unroll
                for (int q = 0; q < 2; q++)
                    acc[mt][q] = __builtin_amdgcn_mfma_f32_16x16x32_bf16(
                        a, bfr[q][kt], acc[mt][q], 0, 0, 0);
            }
        }
#pragma unroll
        for (int q = 0; q < 2; q++) {
            int nt = 2 * wv + q;
            int col = (j0 + nt * 4 + (l15 >> 2)) * 4 + (l15 & 3);
#pragma unroll
            for (int mt = 0; mt < 4; mt++) {
#pragma unroll
                for (int r = 0; r < 4; r++) {
                    int b = mt * 16 + lq * 4 + r;
                    xw[((size_t)b * SENT_LEN + t) * 1024 + col] =
                        f2bfu((acc[mt][q][r] + bb[q]) * LOG2E);
                }
            }
        }
    }
}

// ---------------- K4: word LSTM. 64 blocks x 1 chain, 1024 threads (16 waves).
// Wave w owns gate types i,f,g,o for dims j = w*16 + l15. bfr[4][4] = 64 VGPR resident.
// A-pack = contiguous h i8 vector (256 B, dbuf); broadcast conflict-free reads.
// xw [b][t][j-gate-interleaved]: contiguous 2KB/step stream; PREFETCH DEPTH 4 steps.
__global__ __launch_bounds__(1024, 1) void word_lstm(
        const uint2* __restrict__ xw8, const signed char* __restrict__ wq,
        const float* __restrict__ sw, float* __restrict__ h_out) {
    int b    = blockIdx.x;               // chain 0..63
    int tid  = threadIdx.x;
    int lane = tid & 63, w = tid >> 6;   // 16 waves
    int l15  = lane & 15, lq = lane >> 4;
    int j    = w * 16 + l15;

    __shared__ __align__(16) signed char hv[2][256];   // h as i8, dbuf, 512 B

    lng2 bfr[4][4];
    float swl[4];
#pragma unroll
    for (int nt = 0; nt < 4; nt++) {
        int g = nt * 256 + j;
        swl[nt] = sw[g] * (LOG2E / 127.f);
#pragma unroll
        for (int kt = 0; kt < 4; kt++)
            bfr[nt][kt] = reinterpret_cast<const lng2*>(wq + (size_t)g * HID + kt * 64 + lq * 16)[0];
    }
    if (tid < 128) { reinterpret_cast<int*>(hv)[tid] = 0; }

    const uint2* xwb = xw8 + (size_t)b * SENT_LEN * 256;   // this block's stream
    float cst = 0.f;
    uint2 xq0 = xwb[0 * 256 + j];
    uint2 xq1 = xwb[1 * 256 + j];
    uint2 xq2 = xwb[2 * 256 + j];
    uint2 xq3 = xwb[3 * 256 + j];
    __syncthreads();

    for (int u = 0; u < 128; u++) {          // steps 2u (A), 2u+1 (B)
        uint2 xn0 = xwb[((((u << 1) + 4) & 255)) * 256 + j];
        uint2 xn1 = xwb[((((u << 1) + 5) & 255)) * 256 + j];

        {   // step A: read hv[0] -> write hv[1]
            const lng2* hp = reinterpret_cast<const lng2*>(hv[0]);
            i32x4 acc[4] = {};
#pragma unroll
            for (int kt = 0; kt < 4; kt++) {
                lng2 a = hp[kt * 4 + lq];
#pragma unroll
                for (int nt = 0; nt < 4; nt++)
                    acc[nt] = mfma_i8_k64(a, bfr[nt][kt], acc[nt]);
            }
            float gi = (float)acc[0][0] * swl[0] + bf_lo(xq0.x);
            float gf = (float)acc[1][0] * swl[1] + bf_hi(xq0.x);
            float gg = (float)acc[2][0] * swl[2] + bf_lo(xq0.y);
            float go = (float)acc[3][0] * swl[3] + bf_hi(xq0.y);
            float h = lstm_act(gi, gf, gg, go, cst);
            if (lq == 0) {
                h_out[((size_t)(u << 1) * SENT_BATCH + b) * HID + j] = h;
                hv[1][j] = (signed char)__float2int_rn(h * 127.f);
            }
            block_sync_lds();
        }
        {   // step B: read hv[1] -> write hv[0]
            const lng2* hp = reinterpret_cast<const lng2*>(hv[1]);
            i32x4 acc[4] = {};
#pragma unroll
            for (int kt = 0; kt < 4; kt++) {
                lng2 a = hp[kt * 4 + lq];
#pragma unroll
                for (int nt = 0; nt < 4; nt++)
                    acc[nt] = mfma_i8_k64(a, bfr[nt][kt], acc[nt]);
            }
            float gi = (float)acc[0][0] * swl[0] + bf_lo(xq1.x);
            float gf = (float)acc[1][0] * swl[1] + bf_hi(xq1.x);
            float gg = (float)acc[2][0] * swl[2] + bf_lo(xq1.y);
            float go = (float)acc[3][0] * swl[3] + bf_hi(xq1.y);
            float h = lstm_act(gi, gf, gg, go, cst);
            if (lq == 0) {
                h_out[((size_t)((u << 1) + 1) * SENT_BATCH + b) * HID + j] = h;
                hv[0][j] = (signed char)__float2int_rn(h * 127.f);
            }
            block_sync_lds();
        }
        xq0 = xq2; xq1 = xq3; xq2 = xn0; xq3 = xn1;
    }
}

// ---------------- K5: tag projection + log_softmax.
__global__ __launch_bounds__(256) void tag_logsoftmax(
        const float* __restrict__ h_out, const float* __restrict__ W_tag,
        const float* __restrict__ b_tag, float* __restrict__ out) {
    __shared__ float wt_s[TAGS * 257];
    __shared__ float hr_s[4 * HID];
    int tid = threadIdx.x;
    int row0 = blockIdx.x * 4;
#pragma unroll 2
    for (int i = 0; i < TAGS; i++) wt_s[i * 257 + tid] = W_tag[i * HID + tid];
#pragma unroll
    for (int w = 0; w < 4; w++) hr_s[w * HID + tid] = h_out[(size_t)(row0 + w) * HID + tid];
    __syncthreads();

    int w = tid >> 6, l = tid & 63;
    float acc = 0.f;
    if (l < TAGS) {
        acc = b_tag[l];
        const float* hr = hr_s + w * HID;
        const float* wr = wt_s + l * 257;
#pragma unroll 4
        for (int k = 0; k < HID; k++) acc += hr[k] * wr[k];
    }
    float m = (l < TAGS) ? acc : -1e30f;
#pragma unroll
    for (int off = 32; off; off >>= 1) m = fmaxf(m, __shfl_xor(m, off, 64));
    float e = (l < TAGS) ? __builtin_amdgcn_exp2f((acc - m) * LOG2E) : 0.f;
    float ssum = e;
#pragma unroll
    for (int off = 32; off; off >>= 1) ssum += __shfl_xor(ssum, off, 64);
    float lse = m + __logf(ssum);
    if (l < TAGS) out[(size_t)(row0 + w) * TAGS + l] = acc - lse;
}

extern "C" void kernel_launch(void* const* d_in, const int* in_sizes, int n_in,
                              void* d_out, int out_size, void* d_ws, size_t ws_size,
                              hipStream_t stream) {
    (void)in_sizes; (void)n_in; (void)out_size; (void)ws_size;
    const int*   sentences = (const int*)d_in[0];
    const int*   words     = (const int*)d_in[1];
    const float* word_emb  = (const float*)d_in[4];
    const float* char_emb  = (const float*)d_in[5];
    const float* Wih_c     = (const float*)d_in[6];
    const float* Whh_c     = (const float*)d_in[7];
    const float* bih_c     = (const float*)d_in[8];
    const float* bhh_c     = (const float*)d_in[9];
    const float* Wih_w     = (const float*)d_in[10];
    const float* Whh_w     = (const float*)d_in[11];
    const float* bih_w     = (const float*)d_in[12];
    const float* bhh_w     = (const float*)d_in[13];
    const float* W_tag     = (const float*)d_in[14];
    const float* b_tag     = (const float*)d_in[15];
    float* out = (float*)d_out;

    char* ws = (char*)d_ws;
    size_t off = 0;
    float* pre8 = (float*)(ws + off);                 off += 128 * 512 * sizeof(float);      // 256 KB
    signed char* wq = (signed char*)(ws + off);       off += 1024 * 256;                     // 256 KB
    float* sw = (float*)(ws + off);                   off += 1024 * sizeof(float);           // 4 KB
    off = (off + 255) & ~(size_t)255;
    float* cf = (float*)(ws + off);                   off += (size_t)SENT_LEN * SENT_BATCH * CHID * sizeof(float); // 8.4 MB
    uint2* xw8 = (uint2*)(ws + off);                  off += (size_t)SENT_LEN * SENT_BATCH * 256 * sizeof(uint2);  // 33.5 MB
    float* h_out = (float*)(ws + off);                off += (size_t)SENT_LEN * SENT_BATCH * HID * sizeof(float);  // 16.8 MB

    hipLaunchKernelGGL(prep_char, dim3(128), dim3(512), 0, stream,
                       Wih_c, char_emb, bih_c, bhh_c, pre8);
    hipLaunchKernelGGL(prep_wq, dim3(1024), dim3(64), 0, stream, Whh_w, wq, sw);
    hipLaunchKernelGGL(char_lstm, dim3(256), dim3(512), 0, stream,
                       words, Whh_c, pre8, cf);
    hipLaunchKernelGGL(xw_gemm, dim3(8, 64), dim3(256), 0, stream,
                       sentences, word_emb, cf, Wih_w, bih_w, bhh_w,
                       (unsigned short*)xw8);
    hipLaunchKernelGGL(word_lstm, dim3(SENT_BATCH), dim3(1024), 0, stream,
                       xw8, wq, sw, h_out);
    hipLaunchKernelGGL(tag_logsoftmax, dim3((SENT_LEN * SENT_BATCH) / 4), dim3(256), 0, stream,
                       h_out, W_tag, b_tag, out);
}

// Round 15
// 1008.567 us; speedup vs baseline: 1.0365x; 1.0365x over previous
//
#include <hip/hip_runtime.h>
#include <hip/hip_bf16.h>
#include <cstdint>

#define SENT_LEN   256
#define SENT_BATCH 64
#define WORD_LEN   16
#define EMB        128
#define HID        256
#define CEMB       64
#define CHID       128
#define TAGS       50
#define K_IN       (EMB + CHID)   // 256
#define LOG2E      1.44269504f

typedef __attribute__((ext_vector_type(8))) short short8;
typedef __attribute__((ext_vector_type(4))) float f32x4;
typedef __attribute__((ext_vector_type(4))) int   i32x4;
typedef __attribute__((ext_vector_type(2))) long  lng2;

__device__ __forceinline__ float rcpf(float x) { return __builtin_amdgcn_rcpf(x); }
// inputs pre-scaled by log2e: sig2(xl) = sigmoid(xl/log2e), tanh2(xl) = tanh(xl/log2e)
__device__ __forceinline__ float sig2(float xl) {
    return rcpf(1.f + __builtin_amdgcn_exp2f(-xl));
}
__device__ __forceinline__ float tanh2(float xl) {
    xl = fminf(fmaxf(xl, -22.f), 22.f);
    float u = __builtin_amdgcn_exp2f(xl + xl);
    return (u - 1.f) * rcpf(u + 1.f);
}
__device__ __forceinline__ float lstm_act(float gi, float gf, float gg, float go, float& cst) {
    float c = sig2(gf) * cst + sig2(gi) * tanh2(gg);
    cst = c;
    return sig2(go) * tanh2(c * LOG2E);
}
__device__ __forceinline__ float bf_lo(unsigned u) { return __uint_as_float(u << 16); }
__device__ __forceinline__ float bf_hi(unsigned u) { return __uint_as_float(u & 0xffff0000u); }
// branch-free RNE bf16 (finite inputs only)
__device__ __forceinline__ unsigned short f2bfu(float f) {
    unsigned u = __float_as_uint(f);
    u += 0x7fff + ((u >> 16) & 1);
    return (unsigned short)(u >> 16);
}
// CK-style barrier: drains LDS (lgkmcnt) only — global prefetches stay in flight.
__device__ __forceinline__ void block_sync_lds() {
    asm volatile("s_waitcnt lgkmcnt(0)\ns_barrier" ::: "memory");
}
// 16-byte K-fragment MFMA as two K=32 i8 calls. Shared A/B k-permutation:
// frag position (lq, half, p) <-> source k = (base) + lq*16 + half*8 + p.
__device__ __forceinline__ i32x4 mfma_i8_k64(lng2 a, lng2 b, i32x4 c) {
    c = __builtin_amdgcn_mfma_i32_16x16x32_i8(a.x, b.x, c, 0, 0, 0);
    return __builtin_amdgcn_mfma_i32_16x16x32_i8(a.y, b.y, c, 0, 0, 0);
}

// ---------------- K1a: pre8[(ch*128+j)*4+gt] = LOG2E*(b_c[g] + Wih_c[g]·char_emb[ch]), g=gt*128+j
__global__ void prep_char(const float* __restrict__ Wih_c, const float* __restrict__ char_emb,
                          const float* __restrict__ bih_c, const float* __restrict__ bhh_c,
                          float* __restrict__ pre8) {
    int ch = blockIdx.x;      // 128
    int g  = threadIdx.x;     // 512
    float acc = bih_c[g] + bhh_c[g];
    const float* w = Wih_c + g * CEMB;
    const float* e = char_emb + ch * CEMB;
#pragma unroll
    for (int k = 0; k < CEMB; k++) acc += w[k] * e[k];
    int gt = g >> 7, j = g & 127;
    pre8[((ch * 128) + j) * 4 + gt] = acc * LOG2E;
}

// ---------------- K1b: per-row i8 quantization of Whh_w. 1024 blocks x 64.
__global__ void prep_wq(const float* __restrict__ Whh_w, signed char* __restrict__ wq,
                        float* __restrict__ sw) {
    int g = blockIdx.x;
    int lane = threadIdx.x;   // 64
    float4 v = reinterpret_cast<const float4*>(Whh_w + (size_t)g * HID)[lane];
    float m = fmaxf(fmaxf(fabsf(v.x), fabsf(v.y)), fmaxf(fabsf(v.z), fabsf(v.w)));
#pragma unroll
    for (int off = 32; off; off >>= 1) m = fmaxf(m, __shfl_xor(m, off, 64));
    m = fmaxf(m, 1e-20f);
    float inv = 127.f / m;
    int q0 = __float2int_rn(v.x * inv), q1 = __float2int_rn(v.y * inv);
    int q2 = __float2int_rn(v.z * inv), q3 = __float2int_rn(v.w * inv);
    int packed = (q0 & 255) | ((q1 & 255) << 8) | ((q2 & 255) << 16) | ((q3 & 255) << 24);
    reinterpret_cast<int*>(wq)[g * 64 + lane] = packed;
    if (lane == 0) sw[g] = m / 127.f;
}

// ---------------- K2: char LSTM. 256 blocks x 1 chain, 512 threads (8 waves).
// Wave w owns gate types i,f,g,o for dims j = w*16 + l15. Whh_c i8 in-kernel quant.
// A-pack = the contiguous h i8 vector (128 B, dbuf). Quad (kt,lq) reads the 16B
// chunk h[kt*64+lq*16 .. +15]: quad-uniform address (LDS broadcast), conflict-free.
__global__ __launch_bounds__(512, 1) void char_lstm(
        const int* __restrict__ words, const float* __restrict__ Whh_c,
        const float* __restrict__ pre8, float* __restrict__ cf) {
    int t    = blockIdx.x;               // chain
    int tid  = threadIdx.x;
    int lane = tid & 63, w = tid >> 6;   // 8 waves
    int l15  = lane & 15, lq = lane >> 4;
    int j    = w * 16 + l15;

    __shared__ __align__(16) signed char hv[2][128];   // h as i8, dbuf, 256 B

    // ---- in-kernel per-row i8 quant of Whh_c; B-frag (nt,kt): k = kt*64 + lq*16 + p
    lng2 bfr[4][2];
    float swl[4];
#pragma unroll
    for (int nt = 0; nt < 4; nt++) {
        const float* wr = Whh_c + (size_t)(nt * 128 + j) * CHID;
        float v[2][16];
        float m = 0.f;
#pragma unroll
        for (int kt = 0; kt < 2; kt++) {
#pragma unroll
            for (int q = 0; q < 4; q++) {
                float4 f = reinterpret_cast<const float4*>(wr + kt * 64 + lq * 16 + q * 4)[0];
                v[kt][q * 4 + 0] = f.x; v[kt][q * 4 + 1] = f.y;
                v[kt][q * 4 + 2] = f.z; v[kt][q * 4 + 3] = f.w;
            }
#pragma unroll
            for (int p = 0; p < 16; p++) m = fmaxf(m, fabsf(v[kt][p]));
        }
        m = fmaxf(m, __shfl_xor(m, 16, 64));
        m = fmaxf(m, __shfl_xor(m, 32, 64));
        m = fmaxf(m, 1e-20f);
        float inv = 127.f / m;
#pragma unroll
        for (int kt = 0; kt < 2; kt++) {
            unsigned long lo = 0, hi = 0;
#pragma unroll
            for (int p = 0; p < 8; p++) {
                lo |= (unsigned long)((unsigned)__float2int_rn(v[kt][p] * inv) & 255) << (8 * p);
                hi |= (unsigned long)((unsigned)__float2int_rn(v[kt][p + 8] * inv) & 255) << (8 * p);
            }
            lng2 bb; bb.x = (long)lo; bb.y = (long)hi;
            bfr[nt][kt] = bb;
        }
        swl[nt] = m * (LOG2E / (127.f * 127.f));
    }
    if (tid < 64) { reinterpret_cast<int*>(hv)[tid] = 0; }

    float cst = 0.f;
    const float4* pre4p = reinterpret_cast<const float4*>(pre8);
    int cid0 = words[t];
    int cid1 = words[SENT_LEN + t];
    float4 pr0 = pre4p[cid0 * 128 + j];
    float4 pr1 = pre4p[cid1 * 128 + j];
    int cidn0 = words[2 * SENT_LEN + t];
    int cidn1 = words[3 * SENT_LEN + t];
    __syncthreads();

    for (int u = 0; u < 512; u++) {          // steps 2u (A), 2u+1 (B)
        float4 prn0 = pre4p[cidn0 * 128 + j];
        float4 prn1 = pre4p[cidn1 * 128 + j];
        cidn0 = words[(((u << 1) + 4) & 1023) * SENT_LEN + t];
        cidn1 = words[(((u << 1) + 5) & 1023) * SENT_LEN + t];

        {   // step A: read hv[0] -> write hv[1]
            const lng2* hp = reinterpret_cast<const lng2*>(hv[0]);
            lng2 a0 = hp[lq];            // h[lq*16 .. +15]
            lng2 a1 = hp[4 + lq];        // h[64 + lq*16 .. +15]
            i32x4 acc[4] = {};
#pragma unroll
            for (int nt = 0; nt < 4; nt++) {
                acc[nt] = mfma_i8_k64(a0, bfr[nt][0], acc[nt]);
                acc[nt] = mfma_i8_k64(a1, bfr[nt][1], acc[nt]);
            }
            float gi = (float)acc[0][0] * swl[0] + pr0.x;
            float gf = (float)acc[1][0] * swl[1] + pr0.y;
            float gg = (float)acc[2][0] * swl[2] + pr0.z;
            float go = (float)acc[3][0] * swl[3] + pr0.w;
            float h = lstm_act(gi, gf, gg, go, cst);
            if (lq == 0)
                hv[1][j] = (signed char)__float2int_rn(h * 127.f);
            block_sync_lds();
        }
        {   // step B: read hv[1] -> write hv[0]
            const lng2* hp = reinterpret_cast<const lng2*>(hv[1]);
            lng2 a0 = hp[lq];
            lng2 a1 = hp[4 + lq];
            i32x4 acc[4] = {};
#pragma unroll
            for (int nt = 0; nt < 4; nt++) {
                acc[nt] = mfma_i8_k64(a0, bfr[nt][0], acc[nt]);
                acc[nt] = mfma_i8_k64(a1, bfr[nt][1], acc[nt]);
            }
            float gi = (float)acc[0][0] * swl[0] + pr1.x;
            float gf = (float)acc[1][0] * swl[1] + pr1.y;
            float gg = (float)acc[2][0] * swl[2] + pr1.z;
            float go = (float)acc[3][0] * swl[3] + pr1.w;
            float h = lstm_act(gi, gf, gg, go, cst);
            if (lq == 0) {
                hv[0][j] = (signed char)__float2int_rn(h * 127.f);
                if ((u & 7) == 7)
                    cf[((size_t)t * SENT_BATCH + (u >> 3)) * CHID + j] = h;
            }
            block_sync_lds();
        }
        pr0 = prn0; pr1 = prn1;
    }
}

// ---------------- K3: bf16 MFMA GEMM (R12 form). xw8[(b*256+t)*256+j] = uint2{bf16 gates}.
// [b][t][j] layout: word_lstm block b streams a contiguous 512 KB region.
#define XW_SEG 65   // 16B units per LDS segment (64 lanes + 1 pad)
__global__ __launch_bounds__(256, 2) void xw_gemm(
        const int* __restrict__ sentences, const float* __restrict__ word_emb,
        const float* __restrict__ cf, const float* __restrict__ Wih_w,
        const float* __restrict__ bih_w, const float* __restrict__ bhh_w,
        uint2* __restrict__ xw8) {
    __shared__ short8 Apack[32 * XW_SEG];   // segment s = kt*4 + wv(m-tile)
    __shared__ short8 Bpack[32 * XW_SEG];   // segment s = kt*4 + nt(gate type)
    __shared__ int sid_s[64];
    int tid = threadIdx.x;
    int j0 = blockIdx.x * 16;
    int row0 = blockIdx.y * 64;             // row0 = t*64: whole block is one t
    if (tid < 64) sid_s[tid] = sentences[row0 + tid];
    __syncthreads();

#pragma unroll
    for (int it = 0; it < 8; it++) {
        int idx = it * 256 + tid;
        int m = idx >> 5, k8 = idx & 31;
        int k = k8 * 8;
        int kt = k8 >> 2, lqs = k8 & 3;
        int lanes = (m & 15) + (lqs << 4);
        int seg = kt * 4 + (m >> 4);
        const float* asrc = (k < EMB)
            ? word_emb + (size_t)sid_s[m] * EMB + k
            : cf + (size_t)(row0 + m) * CHID + (k - EMB);
        float4 a0 = reinterpret_cast<const float4*>(asrc)[0];
        float4 a1 = reinterpret_cast<const float4*>(asrc)[1];
        short8 av;
        av[0] = (short)f2bfu(a0.x); av[1] = (short)f2bfu(a0.y);
        av[2] = (short)f2bfu(a0.z); av[3] = (short)f2bfu(a0.w);
        av[4] = (short)f2bfu(a1.x); av[5] = (short)f2bfu(a1.y);
        av[6] = (short)f2bfu(a1.z); av[7] = (short)f2bfu(a1.w);
        Apack[seg * XW_SEG + lanes] = av;
        const float* bsrc = Wih_w + (size_t)((m >> 4) * 256 + j0 + (m & 15)) * K_IN + k;
        float4 b0 = reinterpret_cast<const float4*>(bsrc)[0];
        float4 b1 = reinterpret_cast<const float4*>(bsrc)[1];
        short8 bv;
        bv[0] = (short)f2bfu(b0.x); bv[1] = (short)f2bfu(b0.y);
        bv[2] = (short)f2bfu(b0.z); bv[3] = (short)f2bfu(b0.w);
        bv[4] = (short)f2bfu(b1.x); bv[5] = (short)f2bfu(b1.y);
        bv[6] = (short)f2bfu(b1.z); bv[7] = (short)f2bfu(b1.w);
        Bpack[seg * XW_SEG + lanes] = bv;
    }
    __syncthreads();

    int lane = tid & 63, wv = tid >> 6, l15 = lane & 15, lq = lane >> 4;
    f32x4 acc[4] = {{0.f,0.f,0.f,0.f},{0.f,0.f,0.f,0.f},{0.f,0.f,0.f,0.f},{0.f,0.f,0.f,0.f}};
#pragma unroll
    for (int kt = 0; kt < 8; kt++) {
        short8 a = Apack[(kt * 4 + wv) * XW_SEG + lane];
#pragma unroll
        for (int nt = 0; nt < 4; nt++)
            acc[nt] = __builtin_amdgcn_mfma_f32_16x16x32_bf16(
                a, Bpack[(kt * 4 + nt) * XW_SEG + lane], acc[nt], 0, 0, 0);
    }
    float bb[4];
#pragma unroll
    for (int nt = 0; nt < 4; nt++)
        bb[nt] = bih_w[nt * 256 + j0 + l15] + bhh_w[nt * 256 + j0 + l15];
    int t = row0 >> 6;
#pragma unroll
    for (int r = 0; r < 4; r++) {
        int b = wv * 16 + lq * 4 + r;       // chain index within this t
        uint2 o;
        o.x = (unsigned)f2bfu((acc[0][r] + bb[0]) * LOG2E)
            | ((unsigned)f2bfu((acc[1][r] + bb[1]) * LOG2E) << 16);
        o.y = (unsigned)f2bfu((acc[2][r] + bb[2]) * LOG2E)
            | ((unsigned)f2bfu((acc[3][r] + bb[3]) * LOG2E) << 16);
        xw8[((size_t)b * SENT_LEN + t) * 256 + j0 + l15] = o;
    }
}

// ---------------- K4: word LSTM. 64 blocks x 1 chain, 1024 threads (16 waves).
// Wave w owns gate types i,f,g,o for dims j = w*16 + l15. bfr[4][4] = 64 VGPR resident.
// A-pack = contiguous h i8 vector (256 B, dbuf); broadcast conflict-free reads.
// xw8 [b][t][j]: contiguous 2KB/step stream; PREFETCH DEPTH 4 (ring of 4 uint2/lane,
// ~2400 cyc in flight — covers HBM latency; depth-2 showed a 20ms serialized outlier).
__global__ __launch_bounds__(1024, 1) void word_lstm(
        const uint2* __restrict__ xw8, const signed char* __restrict__ wq,
        const float* __restrict__ sw, float* __restrict__ h_out) {
    int b    = blockIdx.x;               // chain 0..63
    int tid  = threadIdx.x;
    int lane = tid & 63, w = tid >> 6;   // 16 waves
    int l15  = lane & 15, lq = lane >> 4;
    int j    = w * 16 + l15;

    __shared__ __align__(16) signed char hv[2][256];   // h as i8, dbuf, 512 B

    lng2 bfr[4][4];
    float swl[4];
#pragma unroll
    for (int nt = 0; nt < 4; nt++) {
        int g = nt * 256 + j;
        swl[nt] = sw[g] * (LOG2E / 127.f);
#pragma unroll
        for (int kt = 0; kt < 4; kt++)
            bfr[nt][kt] = reinterpret_cast<const lng2*>(wq + (size_t)g * HID + kt * 64 + lq * 16)[0];
    }
    if (tid < 128) { reinterpret_cast<int*>(hv)[tid] = 0; }

    const uint2* xwb = xw8 + (size_t)b * SENT_LEN * 256;   // this block's stream
    float cst = 0.f;
    uint2 xq0 = xwb[0 * 256 + j];
    uint2 xq1 = xwb[1 * 256 + j];
    uint2 xq2 = xwb[2 * 256 + j];
    uint2 xq3 = xwb[3 * 256 + j];
    __syncthreads();

    for (int u = 0; u < 128; u++) {          // steps 2u (A), 2u+1 (B)
        uint2 xn0 = xwb[((((u << 1) + 4) & 255)) * 256 + j];
        uint2 xn1 = xwb[((((u << 1) + 5) & 255)) * 256 + j];

        {   // step A: read hv[0] -> write hv[1]
            const lng2* hp = reinterpret_cast<const lng2*>(hv[0]);
            i32x4 acc[4] = {};
#pragma unroll
            for (int kt = 0; kt < 4; kt++) {
                lng2 a = hp[kt * 4 + lq];
#pragma unroll
                for (int nt = 0; nt < 4; nt++)
                    acc[nt] = mfma_i8_k64(a, bfr[nt][kt], acc[nt]);
            }
            float gi = (float)acc[0][0] * swl[0] + bf_lo(xq0.x);
            float gf = (float)acc[1][0] * swl[1] + bf_hi(xq0.x);
            float gg = (float)acc[2][0] * swl[2] + bf_lo(xq0.y);
            float go = (float)acc[3][0] * swl[3] + bf_hi(xq0.y);
            float h = lstm_act(gi, gf, gg, go, cst);
            if (lq == 0) {
                h_out[((size_t)(u << 1) * SENT_BATCH + b) * HID + j] = h;
                hv[1][j] = (signed char)__float2int_rn(h * 127.f);
            }
            block_sync_lds();
        }
        {   // step B: read hv[1] -> write hv[0]
            const lng2* hp = reinterpret_cast<const lng2*>(hv[1]);
            i32x4 acc[4] = {};
#pragma unroll
            for (int kt = 0; kt < 4; kt++) {
                lng2 a = hp[kt * 4 + lq];
#pragma unroll
                for (int nt = 0; nt < 4; nt++)
                    acc[nt] = mfma_i8_k64(a, bfr[nt][kt], acc[nt]);
            }
            float gi = (float)acc[0][0] * swl[0] + bf_lo(xq1.x);
            float gf = (float)acc[1][0] * swl[1] + bf_hi(xq1.x);
            float gg = (float)acc[2][0] * swl[2] + bf_lo(xq1.y);
            float go = (float)acc[3][0] * swl[3] + bf_hi(xq1.y);
            float h = lstm_act(gi, gf, gg, go, cst);
            if (lq == 0) {
                h_out[((size_t)((u << 1) + 1) * SENT_BATCH + b) * HID + j] = h;
                hv[0][j] = (signed char)__float2int_rn(h * 127.f);
            }
            block_sync_lds();
        }
        xq0 = xq2; xq1 = xq3; xq2 = xn0; xq3 = xn1;
    }
}

// ---------------- K5: tag projection + log_softmax.
__global__ __launch_bounds__(256) void tag_logsoftmax(
        const float* __restrict__ h_out, const float* __restrict__ W_tag,
        const float* __restrict__ b_tag, float* __restrict__ out) {
    __shared__ float wt_s[TAGS * 257];
    __shared__ float hr_s[4 * HID];
    int tid = threadIdx.x;
    int row0 = blockIdx.x * 4;
#pragma unroll 2
    for (int i = 0; i < TAGS; i++) wt_s[i * 257 + tid] = W_tag[i * HID + tid];
#pragma unroll
    for (int w = 0; w < 4; w++) hr_s[w * HID + tid] = h_out[(size_t)(row0 + w) * HID + tid];
    __syncthreads();

    int w = tid >> 6, l = tid & 63;
    float acc = 0.f;
    if (l < TAGS) {
        acc = b_tag[l];
        const float* hr = hr_s + w * HID;
        const float* wr = wt_s + l * 257;
#pragma unroll 4
        for (int k = 0; k < HID; k++) acc += hr[k] * wr[k];
    }
    float m = (l < TAGS) ? acc : -1e30f;
#pragma unroll
    for (int off = 32; off; off >>= 1) m = fmaxf(m, __shfl_xor(m, off, 64));
    float e = (l < TAGS) ? __builtin_amdgcn_exp2f((acc - m) * LOG2E) : 0.f;
    float ssum = e;
#pragma unroll
    for (int off = 32; off; off >>= 1) ssum += __shfl_xor(ssum, off, 64);
    float lse = m + __logf(ssum);
    if (l < TAGS) out[(size_t)(row0 + w) * TAGS + l] = acc - lse;
}

extern "C" void kernel_launch(void* const* d_in, const int* in_sizes, int n_in,
                              void* d_out, int out_size, void* d_ws, size_t ws_size,
                              hipStream_t stream) {
    (void)in_sizes; (void)n_in; (void)out_size; (void)ws_size;
    const int*   sentences = (const int*)d_in[0];
    const int*   words     = (const int*)d_in[1];
    const float* word_emb  = (const float*)d_in[4];
    const float* char_emb  = (const float*)d_in[5];
    const float* Wih_c     = (const float*)d_in[6];
    const float* Whh_c     = (const float*)d_in[7];
    const float* bih_c     = (const float*)d_in[8];
    const float* bhh_c     = (const float*)d_in[9];
    const float* Wih_w     = (const float*)d_in[10];
    const float* Whh_w     = (const float*)d_in[11];
    const float* bih_w     = (const float*)d_in[12];
    const float* bhh_w     = (const float*)d_in[13];
    const float* W_tag     = (const float*)d_in[14];
    const float* b_tag     = (const float*)d_in[15];
    float* out = (float*)d_out;

    char* ws = (char*)d_ws;
    size_t off = 0;
    float* pre8 = (float*)(ws + off);                 off += 128 * 512 * sizeof(float);      // 256 KB
    signed char* wq = (signed char*)(ws + off);       off += 1024 * 256;                     // 256 KB
    float* sw = (float*)(ws + off);                   off += 1024 * sizeof(float);           // 4 KB
    off = (off + 255) & ~(size_t)255;
    float* cf = (float*)(ws + off);                   off += (size_t)SENT_LEN * SENT_BATCH * CHID * sizeof(float); // 8.4 MB
    uint2* xw8 = (uint2*)(ws + off);                  off += (size_t)SENT_LEN * SENT_BATCH * 256 * sizeof(uint2);  // 33.5 MB
    float* h_out = (float*)(ws + off);                off += (size_t)SENT_LEN * SENT_BATCH * HID * sizeof(float);  // 16.8 MB

    hipLaunchKernelGGL(prep_char, dim3(128), dim3(512), 0, stream,
                       Wih_c, char_emb, bih_c, bhh_c, pre8);
    hipLaunchKernelGGL(prep_wq, dim3(1024), dim3(64), 0, stream, Whh_w, wq, sw);
    hipLaunchKernelGGL(char_lstm, dim3(256), dim3(512), 0, stream,
                       words, Whh_c, pre8, cf);
    hipLaunchKernelGGL(xw_gemm, dim3(16, 256), dim3(256), 0, stream,
                       sentences, word_emb, cf, Wih_w, bih_w, bhh_w, xw8);
    hipLaunchKernelGGL(word_lstm, dim3(SENT_BATCH), dim3(1024), 0, stream,
                       xw8, wq, sw, h_out);
    hipLaunchKernelGGL(tag_logsoftmax, dim3((SENT_LEN * SENT_BATCH) / 4), dim3(256), 0, stream,
                       h_out, W_tag, b_tag, out);
}

// Round 16
// 974.974 us; speedup vs baseline: 1.0722x; 1.0345x over previous
//
#include <hip/hip_runtime.h>
#include <hip/hip_bf16.h>
#include <cstdint>

#define SENT_LEN   256
#define SENT_BATCH 64
#define WORD_LEN   16
#define EMB        128
#define HID        256
#define CEMB       64
#define CHID       128
#define TAGS       50
#define K_IN       (EMB + CHID)   // 256
#define LOG2E      1.44269504f
#define N2LOG2E    -2.88539008f   // -2*log2(e)

typedef __attribute__((ext_vector_type(8))) short short8;
typedef __attribute__((ext_vector_type(4))) float f32x4;
typedef __attribute__((ext_vector_type(4))) int   i32x4;
typedef __attribute__((ext_vector_type(2))) long  lng2;

__device__ __forceinline__ float rcpf(float x) { return __builtin_amdgcn_rcpf(x); }
// inputs pre-scaled by log2e: sig2(xl) = sigmoid(xl/log2e)
__device__ __forceinline__ float sig2(float xl) {
    return rcpf(1.f + __builtin_amdgcn_exp2f(-xl));
}
// tanh via sigmoid identity, clamp-free: tanh(x) = 2*sigmoid(2x)-1.
// xl = x*log2e  ->  tanh = 2*rcp(1+exp2(-2*xl)) - 1. exp2 saturates naturally.
__device__ __forceinline__ float tanh2(float xl) {
    float e = __builtin_amdgcn_exp2f(-(xl + xl));
    return 2.f * rcpf(1.f + e) - 1.f;
}
__device__ __forceinline__ float lstm_act(float gi, float gf, float gg, float go, float& cst) {
    float c = sig2(gf) * cst + sig2(gi) * tanh2(gg);
    cst = c;
    // tanh(c) with natural-scale c: fused constant -2*log2e
    float tc = 2.f * rcpf(1.f + __builtin_amdgcn_exp2f(N2LOG2E * c)) - 1.f;
    return sig2(go) * tc;
}
__device__ __forceinline__ float bf_lo(unsigned u) { return __uint_as_float(u << 16); }
__device__ __forceinline__ float bf_hi(unsigned u) { return __uint_as_float(u & 0xffff0000u); }
// branch-free RNE bf16 (finite inputs only)
__device__ __forceinline__ unsigned short f2bfu(float f) {
    unsigned u = __float_as_uint(f);
    u += 0x7fff + ((u >> 16) & 1);
    return (unsigned short)(u >> 16);
}
// CK-style barrier: drains LDS (lgkmcnt) only — global prefetches stay in flight.
__device__ __forceinline__ void block_sync_lds() {
    asm volatile("s_waitcnt lgkmcnt(0)\ns_barrier" ::: "memory");
}
// 16-byte K-fragment MFMA as two K=32 i8 calls. Shared A/B k-permutation:
// frag position (lq, half, p) <-> source k = (base) + lq*16 + half*8 + p.
__device__ __forceinline__ i32x4 mfma_i8_k64(lng2 a, lng2 b, i32x4 c) {
    c = __builtin_amdgcn_mfma_i32_16x16x32_i8(a.x, b.x, c, 0, 0, 0);
    return __builtin_amdgcn_mfma_i32_16x16x32_i8(a.y, b.y, c, 0, 0, 0);
}

// ---------------- K1a: pre8[(ch*128+j)*4+gt] = LOG2E*(b_c[g] + Wih_c[g]·char_emb[ch]), g=gt*128+j
__global__ void prep_char(const float* __restrict__ Wih_c, const float* __restrict__ char_emb,
                          const float* __restrict__ bih_c, const float* __restrict__ bhh_c,
                          float* __restrict__ pre8) {
    int ch = blockIdx.x;      // 128
    int g  = threadIdx.x;     // 512
    float acc = bih_c[g] + bhh_c[g];
    const float* w = Wih_c + g * CEMB;
    const float* e = char_emb + ch * CEMB;
#pragma unroll
    for (int k = 0; k < CEMB; k++) acc += w[k] * e[k];
    int gt = g >> 7, j = g & 127;
    pre8[((ch * 128) + j) * 4 + gt] = acc * LOG2E;
}

// ---------------- K1b: per-row i8 quantization of Whh_w. 1024 blocks x 64.
__global__ void prep_wq(const float* __restrict__ Whh_w, signed char* __restrict__ wq,
                        float* __restrict__ sw) {
    int g = blockIdx.x;
    int lane = threadIdx.x;   // 64
    float4 v = reinterpret_cast<const float4*>(Whh_w + (size_t)g * HID)[lane];
    float m = fmaxf(fmaxf(fabsf(v.x), fabsf(v.y)), fmaxf(fabsf(v.z), fabsf(v.w)));
#pragma unroll
    for (int off = 32; off; off >>= 1) m = fmaxf(m, __shfl_xor(m, off, 64));
    m = fmaxf(m, 1e-20f);
    float inv = 127.f / m;
    int q0 = __float2int_rn(v.x * inv), q1 = __float2int_rn(v.y * inv);
    int q2 = __float2int_rn(v.z * inv), q3 = __float2int_rn(v.w * inv);
    int packed = (q0 & 255) | ((q1 & 255) << 8) | ((q2 & 255) << 16) | ((q3 & 255) << 24);
    reinterpret_cast<int*>(wq)[g * 64 + lane] = packed;
    if (lane == 0) sw[g] = m / 127.f;
}

// ---------------- K2: char LSTM. 256 blocks x 1 chain, 512 threads (8 waves).
// Wave w owns gate types i,f,g,o for dims j = w*16 + l15. Whh_c i8 in-kernel quant.
// A-pack = the contiguous h i8 vector (128 B, dbuf). Quad (kt,lq) reads the 16B
// chunk h[kt*64+lq*16 .. +15]: quad-uniform address (LDS broadcast), conflict-free.
__global__ __launch_bounds__(512, 1) void char_lstm(
        const int* __restrict__ words, const float* __restrict__ Whh_c,
        const float* __restrict__ pre8, float* __restrict__ cf) {
    int t    = blockIdx.x;               // chain
    int tid  = threadIdx.x;
    int lane = tid & 63, w = tid >> 6;   // 8 waves
    int l15  = lane & 15, lq = lane >> 4;
    int j    = w * 16 + l15;

    __shared__ __align__(16) signed char hv[2][128];   // h as i8, dbuf, 256 B

    // ---- in-kernel per-row i8 quant of Whh_c; B-frag (nt,kt): k = kt*64 + lq*16 + p
    lng2 bfr[4][2];
    float swl[4];
#pragma unroll
    for (int nt = 0; nt < 4; nt++) {
        const float* wr = Whh_c + (size_t)(nt * 128 + j) * CHID;
        float v[2][16];
        float m = 0.f;
#pragma unroll
        for (int kt = 0; kt < 2; kt++) {
#pragma unroll
            for (int q = 0; q < 4; q++) {
                float4 f = reinterpret_cast<const float4*>(wr + kt * 64 + lq * 16 + q * 4)[0];
                v[kt][q * 4 + 0] = f.x; v[kt][q * 4 + 1] = f.y;
                v[kt][q * 4 + 2] = f.z; v[kt][q * 4 + 3] = f.w;
            }
#pragma unroll
            for (int p = 0; p < 16; p++) m = fmaxf(m, fabsf(v[kt][p]));
        }
        m = fmaxf(m, __shfl_xor(m, 16, 64));
        m = fmaxf(m, __shfl_xor(m, 32, 64));
        m = fmaxf(m, 1e-20f);
        float inv = 127.f / m;
#pragma unroll
        for (int kt = 0; kt < 2; kt++) {
            unsigned long lo = 0, hi = 0;
#pragma unroll
            for (int p = 0; p < 8; p++) {
                lo |= (unsigned long)((unsigned)__float2int_rn(v[kt][p] * inv) & 255) << (8 * p);
                hi |= (unsigned long)((unsigned)__float2int_rn(v[kt][p + 8] * inv) & 255) << (8 * p);
            }
            lng2 bb; bb.x = (long)lo; bb.y = (long)hi;
            bfr[nt][kt] = bb;
        }
        swl[nt] = m * (LOG2E / (127.f * 127.f));
    }
    if (tid < 64) { reinterpret_cast<int*>(hv)[tid] = 0; }

    float cst = 0.f;
    const float4* pre4p = reinterpret_cast<const float4*>(pre8);
    int cid0 = words[t];
    int cid1 = words[SENT_LEN + t];
    float4 pr0 = pre4p[cid0 * 128 + j];
    float4 pr1 = pre4p[cid1 * 128 + j];
    int cidn0 = words[2 * SENT_LEN + t];
    int cidn1 = words[3 * SENT_LEN + t];
    __syncthreads();

    for (int u = 0; u < 512; u++) {          // steps 2u (A), 2u+1 (B)
        float4 prn0 = pre4p[cidn0 * 128 + j];
        float4 prn1 = pre4p[cidn1 * 128 + j];
        cidn0 = words[(((u << 1) + 4) & 1023) * SENT_LEN + t];
        cidn1 = words[(((u << 1) + 5) & 1023) * SENT_LEN + t];

        {   // step A: read hv[0] -> write hv[1]
            const lng2* hp = reinterpret_cast<const lng2*>(hv[0]);
            lng2 a0 = hp[lq];            // h[lq*16 .. +15]
            lng2 a1 = hp[4 + lq];        // h[64 + lq*16 .. +15]
            i32x4 acc[4] = {};
#pragma unroll
            for (int nt = 0; nt < 4; nt++) {
                acc[nt] = mfma_i8_k64(a0, bfr[nt][0], acc[nt]);
                acc[nt] = mfma_i8_k64(a1, bfr[nt][1], acc[nt]);
            }
            float gi = (float)acc[0][0] * swl[0] + pr0.x;
            float gf = (float)acc[1][0] * swl[1] + pr0.y;
            float gg = (float)acc[2][0] * swl[2] + pr0.z;
            float go = (float)acc[3][0] * swl[3] + pr0.w;
            float h = lstm_act(gi, gf, gg, go, cst);
            if (lq == 0)
                hv[1][j] = (signed char)__float2int_rn(h * 127.f);
            block_sync_lds();
        }
        {   // step B: read hv[1] -> write hv[0]
            const lng2* hp = reinterpret_cast<const lng2*>(hv[1]);
            lng2 a0 = hp[lq];
            lng2 a1 = hp[4 + lq];
            i32x4 acc[4] = {};
#pragma unroll
            for (int nt = 0; nt < 4; nt++) {
                acc[nt] = mfma_i8_k64(a0, bfr[nt][0], acc[nt]);
                acc[nt] = mfma_i8_k64(a1, bfr[nt][1], acc[nt]);
            }
            float gi = (float)acc[0][0] * swl[0] + pr1.x;
            float gf = (float)acc[1][0] * swl[1] + pr1.y;
            float gg = (float)acc[2][0] * swl[2] + pr1.z;
            float go = (float)acc[3][0] * swl[3] + pr1.w;
            float h = lstm_act(gi, gf, gg, go, cst);
            if (lq == 0) {
                hv[0][j] = (signed char)__float2int_rn(h * 127.f);
                if ((u & 7) == 7)
                    cf[((size_t)t * SENT_BATCH + (u >> 3)) * CHID + j] = h;
            }
            block_sync_lds();
        }
        pr0 = prn0; pr1 = prn1;
    }
}

// ---------------- K3: bf16 MFMA GEMM (R12 form). xw8[(b*256+t)*256+j] = uint2{bf16 gates}.
// [b][t][j] layout: word_lstm block b streams a contiguous 512 KB region.
#define XW_SEG 65   // 16B units per LDS segment (64 lanes + 1 pad)
__global__ __launch_bounds__(256, 2) void xw_gemm(
        const int* __restrict__ sentences, const float* __restrict__ word_emb,
        const float* __restrict__ cf, const float* __restrict__ Wih_w,
        const float* __restrict__ bih_w, const float* __restrict__ bhh_w,
        uint2* __restrict__ xw8) {
    __shared__ short8 Apack[32 * XW_SEG];   // segment s = kt*4 + wv(m-tile)
    __shared__ short8 Bpack[32 * XW_SEG];   // segment s = kt*4 + nt(gate type)
    __shared__ int sid_s[64];
    int tid = threadIdx.x;
    int j0 = blockIdx.x * 16;
    int row0 = blockIdx.y * 64;             // row0 = t*64: whole block is one t
    if (tid < 64) sid_s[tid] = sentences[row0 + tid];
    __syncthreads();

#pragma unroll
    for (int it = 0; it < 8; it++) {
        int idx = it * 256 + tid;
        int m = idx >> 5, k8 = idx & 31;
        int k = k8 * 8;
        int kt = k8 >> 2, lqs = k8 & 3;
        int lanes = (m & 15) + (lqs << 4);
        int seg = kt * 4 + (m >> 4);
        const float* asrc = (k < EMB)
            ? word_emb + (size_t)sid_s[m] * EMB + k
            : cf + (size_t)(row0 + m) * CHID + (k - EMB);
        float4 a0 = reinterpret_cast<const float4*>(asrc)[0];
        float4 a1 = reinterpret_cast<const float4*>(asrc)[1];
        short8 av;
        av[0] = (short)f2bfu(a0.x); av[1] = (short)f2bfu(a0.y);
        av[2] = (short)f2bfu(a0.z); av[3] = (short)f2bfu(a0.w);
        av[4] = (short)f2bfu(a1.x); av[5] = (short)f2bfu(a1.y);
        av[6] = (short)f2bfu(a1.z); av[7] = (short)f2bfu(a1.w);
        Apack[seg * XW_SEG + lanes] = av;
        const float* bsrc = Wih_w + (size_t)((m >> 4) * 256 + j0 + (m & 15)) * K_IN + k;
        float4 b0 = reinterpret_cast<const float4*>(bsrc)[0];
        float4 b1 = reinterpret_cast<const float4*>(bsrc)[1];
        short8 bv;
        bv[0] = (short)f2bfu(b0.x); bv[1] = (short)f2bfu(b0.y);
        bv[2] = (short)f2bfu(b0.z); bv[3] = (short)f2bfu(b0.w);
        bv[4] = (short)f2bfu(b1.x); bv[5] = (short)f2bfu(b1.y);
        bv[6] = (short)f2bfu(b1.z); bv[7] = (short)f2bfu(b1.w);
        Bpack[seg * XW_SEG + lanes] = bv;
    }
    __syncthreads();

    int lane = tid & 63, wv = tid >> 6, l15 = lane & 15, lq = lane >> 4;
    f32x4 acc[4] = {{0.f,0.f,0.f,0.f},{0.f,0.f,0.f,0.f},{0.f,0.f,0.f,0.f},{0.f,0.f,0.f,0.f}};
#pragma unroll
    for (int kt = 0; kt < 8; kt++) {
        short8 a = Apack[(kt * 4 + wv) * XW_SEG + lane];
#pragma unroll
        for (int nt = 0; nt < 4; nt++)
            acc[nt] = __builtin_amdgcn_mfma_f32_16x16x32_bf16(
                a, Bpack[(kt * 4 + nt) * XW_SEG + lane], acc[nt], 0, 0, 0);
    }
    float bb[4];
#pragma unroll
    for (int nt = 0; nt < 4; nt++)
        bb[nt] = bih_w[nt * 256 + j0 + l15] + bhh_w[nt * 256 + j0 + l15];
    int t = row0 >> 6;
#pragma unroll
    for (int r = 0; r < 4; r++) {
        int b = wv * 16 + lq * 4 + r;       // chain index within this t
        uint2 o;
        o.x = (unsigned)f2bfu((acc[0][r] + bb[0]) * LOG2E)
            | ((unsigned)f2bfu((acc[1][r] + bb[1]) * LOG2E) << 16);
        o.y = (unsigned)f2bfu((acc[2][r] + bb[2]) * LOG2E)
            | ((unsigned)f2bfu((acc[3][r] + bb[3]) * LOG2E) << 16);
        xw8[((size_t)b * SENT_LEN + t) * 256 + j0 + l15] = o;
    }
}

// ---------------- K4: word LSTM. 64 blocks x 1 chain, 1024 threads (16 waves).
// Wave w owns gate types i,f,g,o for dims j = w*16 + l15. bfr[4][4] = 64 VGPR resident.
// A-pack = contiguous h i8 vector (256 B, dbuf); broadcast conflict-free reads.
// xw8 [b][t][j]: contiguous 2KB/step stream; prefetch depth 4 (ring of 4 uint2/lane).
__global__ __launch_bounds__(1024, 1) void word_lstm(
        const uint2* __restrict__ xw8, const signed char* __restrict__ wq,
        const float* __restrict__ sw, float* __restrict__ h_out) {
    int b    = blockIdx.x;               // chain 0..63
    int tid  = threadIdx.x;
    int lane = tid & 63, w = tid >> 6;   // 16 waves
    int l15  = lane & 15, lq = lane >> 4;
    int j    = w * 16 + l15;

    __shared__ __align__(16) signed char hv[2][256];   // h as i8, dbuf, 512 B

    lng2 bfr[4][4];
    float swl[4];
#pragma unroll
    for (int nt = 0; nt < 4; nt++) {
        int g = nt * 256 + j;
        swl[nt] = sw[g] * (LOG2E / 127.f);
#pragma unroll
        for (int kt = 0; kt < 4; kt++)
            bfr[nt][kt] = reinterpret_cast<const lng2*>(wq + (size_t)g * HID + kt * 64 + lq * 16)[0];
    }
    if (tid < 128) { reinterpret_cast<int*>(hv)[tid] = 0; }

    const uint2* xwb = xw8 + (size_t)b * SENT_LEN * 256;   // this block's stream
    float cst = 0.f;
    uint2 xq0 = xwb[0 * 256 + j];
    uint2 xq1 = xwb[1 * 256 + j];
    uint2 xq2 = xwb[2 * 256 + j];
    uint2 xq3 = xwb[3 * 256 + j];
    __syncthreads();

    for (int u = 0; u < 128; u++) {          // steps 2u (A), 2u+1 (B)
        uint2 xn0 = xwb[((((u << 1) + 4) & 255)) * 256 + j];
        uint2 xn1 = xwb[((((u << 1) + 5) & 255)) * 256 + j];

        {   // step A: read hv[0] -> write hv[1]
            const lng2* hp = reinterpret_cast<const lng2*>(hv[0]);
            i32x4 acc[4] = {};
#pragma unroll
            for (int kt = 0; kt < 4; kt++) {
                lng2 a = hp[kt * 4 + lq];
#pragma unroll
                for (int nt = 0; nt < 4; nt++)
                    acc[nt] = mfma_i8_k64(a, bfr[nt][kt], acc[nt]);
            }
            float gi = (float)acc[0][0] * swl[0] + bf_lo(xq0.x);
            float gf = (float)acc[1][0] * swl[1] + bf_hi(xq0.x);
            float gg = (float)acc[2][0] * swl[2] + bf_lo(xq0.y);
            float go = (float)acc[3][0] * swl[3] + bf_hi(xq0.y);
            float h = lstm_act(gi, gf, gg, go, cst);
            if (lq == 0) {
                h_out[((size_t)(u << 1) * SENT_BATCH + b) * HID + j] = h;
                hv[1][j] = (signed char)__float2int_rn(h * 127.f);
            }
            block_sync_lds();
        }
        {   // step B: read hv[1] -> write hv[0]
            const lng2* hp = reinterpret_cast<const lng2*>(hv[1]);
            i32x4 acc[4] = {};
#pragma unroll
            for (int kt = 0; kt < 4; kt++) {
                lng2 a = hp[kt * 4 + lq];
#pragma unroll
                for (int nt = 0; nt < 4; nt++)
                    acc[nt] = mfma_i8_k64(a, bfr[nt][kt], acc[nt]);
            }
            float gi = (float)acc[0][0] * swl[0] + bf_lo(xq1.x);
            float gf = (float)acc[1][0] * swl[1] + bf_hi(xq1.x);
            float gg = (float)acc[2][0] * swl[2] + bf_lo(xq1.y);
            float go = (float)acc[3][0] * swl[3] + bf_hi(xq1.y);
            float h = lstm_act(gi, gf, gg, go, cst);
            if (lq == 0) {
                h_out[((size_t)((u << 1) + 1) * SENT_BATCH + b) * HID + j] = h;
                hv[0][j] = (signed char)__float2int_rn(h * 127.f);
            }
            block_sync_lds();
        }
        xq0 = xq2; xq1 = xq3; xq2 = xn0; xq3 = xn1;
    }
}

// ---------------- K5: tag projection + log_softmax.
__global__ __launch_bounds__(256) void tag_logsoftmax(
        const float* __restrict__ h_out, const float* __restrict__ W_tag,
        const float* __restrict__ b_tag, float* __restrict__ out) {
    __shared__ float wt_s[TAGS * 257];
    __shared__ float hr_s[4 * HID];
    int tid = threadIdx.x;
    int row0 = blockIdx.x * 4;
#pragma unroll 2
    for (int i = 0; i < TAGS; i++) wt_s[i * 257 + tid] = W_tag[i * HID + tid];
#pragma unroll
    for (int w = 0; w < 4; w++) hr_s[w * HID + tid] = h_out[(size_t)(row0 + w) * HID + tid];
    __syncthreads();

    int w = tid >> 6, l = tid & 63;
    float acc = 0.f;
    if (l < TAGS) {
        acc = b_tag[l];
        const float* hr = hr_s + w * HID;
        const float* wr = wt_s + l * 257;
#pragma unroll 4
        for (int k = 0; k < HID; k++) acc += hr[k] * wr[k];
    }
    float m = (l < TAGS) ? acc : -1e30f;
#pragma unroll
    for (int off = 32; off; off >>= 1) m = fmaxf(m, __shfl_xor(m, off, 64));
    float e = (l < TAGS) ? __builtin_amdgcn_exp2f((acc - m) * LOG2E) : 0.f;
    float ssum = e;
#pragma unroll
    for (int off = 32; off; off >>= 1) ssum += __shfl_xor(ssum, off, 64);
    float lse = m + __logf(ssum);
    if (l < TAGS) out[(size_t)(row0 + w) * TAGS + l] = acc - lse;
}

extern "C" void kernel_launch(void* const* d_in, const int* in_sizes, int n_in,
                              void* d_out, int out_size, void* d_ws, size_t ws_size,
                              hipStream_t stream) {
    (void)in_sizes; (void)n_in; (void)out_size; (void)ws_size;
    const int*   sentences = (const int*)d_in[0];
    const int*   words     = (const int*)d_in[1];
    const float* word_emb  = (const float*)d_in[4];
    const float* char_emb  = (const float*)d_in[5];
    const float* Wih_c     = (const float*)d_in[6];
    const float* Whh_c     = (const float*)d_in[7];
    const float* bih_c     = (const float*)d_in[8];
    const float* bhh_c     = (const float*)d_in[9];
    const float* Wih_w     = (const float*)d_in[10];
    const float* Whh_w     = (const float*)d_in[11];
    const float* bih_w     = (const float*)d_in[12];
    const float* bhh_w     = (const float*)d_in[13];
    const float* W_tag     = (const float*)d_in[14];
    const float* b_tag     = (const float*)d_in[15];
    float* out = (float*)d_out;

    char* ws = (char*)d_ws;
    size_t off = 0;
    float* pre8 = (float*)(ws + off);                 off += 128 * 512 * sizeof(float);      // 256 KB
    signed char* wq = (signed char*)(ws + off);       off += 1024 * 256;                     // 256 KB
    float* sw = (float*)(ws + off);                   off += 1024 * sizeof(float);           // 4 KB
    off = (off + 255) & ~(size_t)255;
    float* cf = (float*)(ws + off);                   off += (size_t)SENT_LEN * SENT_BATCH * CHID * sizeof(float); // 8.4 MB
    uint2* xw8 = (uint2*)(ws + off);                  off += (size_t)SENT_LEN * SENT_BATCH * 256 * sizeof(uint2);  // 33.5 MB
    float* h_out = (float*)(ws + off);                off += (size_t)SENT_LEN * SENT_BATCH * HID * sizeof(float);  // 16.8 MB

    hipLaunchKernelGGL(prep_char, dim3(128), dim3(512), 0, stream,
                       Wih_c, char_emb, bih_c, bhh_c, pre8);
    hipLaunchKernelGGL(prep_wq, dim3(1024), dim3(64), 0, stream, Whh_w, wq, sw);
    hipLaunchKernelGGL(char_lstm, dim3(256), dim3(512), 0, stream,
                       words, Whh_c, pre8, cf);
    hipLaunchKernelGGL(xw_gemm, dim3(16, 256), dim3(256), 0, stream,
                       sentences, word_emb, cf, Wih_w, bih_w, bhh_w, xw8);
    hipLaunchKernelGGL(word_lstm, dim3(SENT_BATCH), dim3(1024), 0, stream,
                       xw8, wq, sw, h_out);
    hipLaunchKernelGGL(tag_logsoftmax, dim3((SENT_LEN * SENT_BATCH) / 4), dim3(256), 0, stream,
                       h_out, W_tag, b_tag, out);
}